// Round 1
// baseline (1842.150 us; speedup 1.0000x reference)
//
#include <hip/hip_runtime.h>

#define BB 128
#define TT 2048
#define II 64
#define HH 128
#define GG 512  // 4*H

typedef _Float16 h2 __attribute__((ext_vector_type(2)));

__device__ __forceinline__ h2 mkh2(float a, float b) {
    h2 r; r.x = (_Float16)a; r.y = (_Float16)b; return r;
}

__device__ __forceinline__ h2 u2h(unsigned u) {
    return __builtin_bit_cast(h2, u);
}

__device__ __forceinline__ float fdot2f(h2 a, h2 b, float c) {
#if __has_builtin(__builtin_amdgcn_fdot2)
    return __builtin_amdgcn_fdot2(a, b, c, false);
#else
    return fmaf((float)a.y, (float)b.y, fmaf((float)a.x, (float)b.x, c));
#endif
}

__device__ __forceinline__ float sigmoid_fast(float x) {
    return __builtin_amdgcn_rcpf(1.0f + __expf(-x));
}
__device__ __forceinline__ float tanh_fast(float x) {
    // tanh(x) = 2*sigmoid(2x) - 1
    return fmaf(__builtin_amdgcn_rcpf(1.0f + __expf(-2.0f * x)), 2.0f, -1.0f);
}

// One workgroup per batch element. Thread g in [0,512) owns gate g.
// W rows live in VGPRs (fp16x2); h/x broadcast via LDS; c in fp32 regs of wave 0.
__global__ __launch_bounds__(512, 2) void lstm_fused_kernel(
    const float* __restrict__ input,  // [B,T,I]
    const float* __restrict__ h0,     // [B,H]
    const float* __restrict__ c0,     // [B,H]
    const float* __restrict__ W_ih,   // [4H,I]
    const float* __restrict__ W_hh,   // [4H,H]
    const float* __restrict__ b_ih,   // [4H]
    const float* __restrict__ b_hh,   // [4H]
    float* __restrict__ out)          // [B*H] h_last, then [B,T,H] encoded
{
    __shared__ __align__(16) h2 s_x[II / 2];   // 32 x fp16x2
    __shared__ __align__(16) h2 s_h[HH / 2];   // 64 x fp16x2
    __shared__ __align__(16) float s_g[GG];    // gate activations

    const int tid = threadIdx.x;
    const int b   = blockIdx.x;

    // ---- load this thread's weight rows into registers, fp32 -> fp16 ----
    h2 wih[II / 2];   // 32 regs
    h2 whh[HH / 2];   // 64 regs
    {
        const float4* p = reinterpret_cast<const float4*>(W_ih + tid * II);
#pragma unroll
        for (int j = 0; j < II / 4; ++j) {
            float4 w = p[j];
            wih[2 * j]     = mkh2(w.x, w.y);
            wih[2 * j + 1] = mkh2(w.z, w.w);
        }
    }
    {
        const float4* p = reinterpret_cast<const float4*>(W_hh + tid * HH);
#pragma unroll
        for (int j = 0; j < HH / 4; ++j) {
            float4 w = p[j];
            whh[2 * j]     = mkh2(w.x, w.y);
            whh[2 * j + 1] = mkh2(w.z, w.w);
        }
    }
    const float bias = b_ih[tid] + b_hh[tid];

    // ---- init h, c (wave 0 handles the 128 h-elements as 64 pairs) ----
    float cc0 = 0.0f, cc1 = 0.0f;
    float2 hl = make_float2(0.0f, 0.0f);
    if (tid < 64) {
        float2 hv = *reinterpret_cast<const float2*>(h0 + b * HH + 2 * tid);
        float2 cv = *reinterpret_cast<const float2*>(c0 + b * HH + 2 * tid);
        cc0 = cv.x; cc1 = cv.y;
        s_h[tid] = mkh2(hv.x, hv.y);
    }

    // ---- x prefetch: threads 0..31 each hold 4 future float2 of x ----
    const float2* xin = reinterpret_cast<const float2*>(input) + (size_t)b * TT * 32 + tid;
    float2 xb0, xb1, xb2, xb3;
    if (tid < 32) {
        xb0 = xin[(size_t)0 * 32];
        xb1 = xin[(size_t)1 * 32];
        xb2 = xin[(size_t)2 * 32];
        xb3 = xin[(size_t)3 * 32];
    }

    float* out_h = out;            // [B*H]
    float* out_e = out + BB * HH;  // [B*T*H]

    auto step = [&](int t, float2& xb) {
        // stage x_t into LDS, prefetch x_{t+4}
        if (tid < 32) {
            s_x[tid] = mkh2(xb.x, xb.y);
            int tn = t + 4; if (tn > TT - 1) tn = TT - 1;  // clamped re-read, harmless
            xb = xin[(size_t)tn * 32];
        }
        __syncthreads();  // B1: s_x and s_h(t) visible

        const uint4* sx4 = reinterpret_cast<const uint4*>(s_x);  // 8 uint4
        const uint4* sh4 = reinterpret_cast<const uint4*>(s_h);  // 16 uint4
        float a0 = bias, a1 = 0.0f, a2 = 0.0f, a3 = 0.0f;
#pragma unroll
        for (int j = 0; j < 8; ++j) {
            uint4 v = sx4[j];
            a0 = fdot2f(wih[4 * j + 0], u2h(v.x), a0);
            a1 = fdot2f(wih[4 * j + 1], u2h(v.y), a1);
            a2 = fdot2f(wih[4 * j + 2], u2h(v.z), a2);
            a3 = fdot2f(wih[4 * j + 3], u2h(v.w), a3);
        }
#pragma unroll
        for (int j = 0; j < 16; ++j) {
            uint4 v = sh4[j];
            a0 = fdot2f(whh[4 * j + 0], u2h(v.x), a0);
            a1 = fdot2f(whh[4 * j + 1], u2h(v.y), a1);
            a2 = fdot2f(whh[4 * j + 2], u2h(v.z), a2);
            a3 = fdot2f(whh[4 * j + 3], u2h(v.w), a3);
        }
        float gate = (a0 + a1) + (a2 + a3);
        // gate type: 0=i 1=f 2=g 3=o ; tid>>7 is wave-uniform (128-aligned)
        float act = ((tid >> 7) == 2) ? tanh_fast(gate) : sigmoid_fast(gate);
        s_g[tid] = act;
        __syncthreads();  // B2: s_g ready; all readers done with s_h/s_x

        if (tid < 64) {  // wave 0: c/h update for element pair (2*tid, 2*tid+1)
            float2 ig = *reinterpret_cast<const float2*>(s_g + 2 * tid);
            float2 fg = *reinterpret_cast<const float2*>(s_g + 128 + 2 * tid);
            float2 gg = *reinterpret_cast<const float2*>(s_g + 256 + 2 * tid);
            float2 og = *reinterpret_cast<const float2*>(s_g + 384 + 2 * tid);
            cc0 = fmaf(fg.x, cc0, ig.x * gg.x);
            cc1 = fmaf(fg.y, cc1, ig.y * gg.y);
            float hv0 = og.x * tanh_fast(cc0);
            float hv1 = og.y * tanh_fast(cc1);
            s_h[tid] = mkh2(hv0, hv1);   // safe: readers passed B2
            hl = make_float2(hv0, hv1);
            *reinterpret_cast<float2*>(out_e + ((size_t)b * TT + t) * HH + 2 * tid) = hl;
        }
    };

    for (int t0 = 0; t0 < TT; t0 += 4) {
        step(t0 + 0, xb0);
        step(t0 + 1, xb1);
        step(t0 + 2, xb2);
        step(t0 + 3, xb3);
    }

    if (tid < 64) {
        *reinterpret_cast<float2*>(out_h + b * HH + 2 * tid) = hl;
    }
}

extern "C" void kernel_launch(void* const* d_in, const int* in_sizes, int n_in,
                              void* d_out, int out_size, void* d_ws, size_t ws_size,
                              hipStream_t stream) {
    const float* input = (const float*)d_in[0];
    const float* h0    = (const float*)d_in[1];
    const float* c0    = (const float*)d_in[2];
    const float* W_ih  = (const float*)d_in[3];
    const float* W_hh  = (const float*)d_in[4];
    const float* b_ih  = (const float*)d_in[5];
    const float* b_hh  = (const float*)d_in[6];
    float* out = (float*)d_out;

    hipLaunchKernelGGL(lstm_fused_kernel, dim3(BB), dim3(GG), 0, stream,
                       input, h0, c0, W_ih, W_hh, b_ih, b_hh, out);
}

// Round 2
// 1607.896 us; speedup vs baseline: 1.1457x; 1.1457x over previous
//
#include <hip/hip_runtime.h>

#define BB 128
#define TT 2048
#define II 64
#define HH 128
#define GG 512  // 4*H

typedef _Float16 h2 __attribute__((ext_vector_type(2)));

__device__ __forceinline__ h2 mkh2(float a, float b) {
    h2 r; r.x = (_Float16)a; r.y = (_Float16)b; return r;
}

__device__ __forceinline__ h2 u2h(unsigned u) {
    return __builtin_bit_cast(h2, u);
}

__device__ __forceinline__ float fdot2f(h2 a, h2 b, float c) {
#if __has_builtin(__builtin_amdgcn_fdot2)
    return __builtin_amdgcn_fdot2(a, b, c, false);
#else
    return fmaf((float)a.y, (float)b.y, fmaf((float)a.x, (float)b.x, c));
#endif
}

__device__ __forceinline__ float rcp_fast(float x) {
    return __builtin_amdgcn_rcpf(x);
}

__device__ __forceinline__ float tanh_fast(float x) {
    // tanh(x) = 2/(1+e^-2x) - 1
    return fmaf(rcp_fast(1.0f + __expf(-2.0f * x)), 2.0f, -1.0f);
}

// DPP quad_perm cross-lane (within groups of 4 lanes), pure VALU — no LDS.
template <int CTRL>
__device__ __forceinline__ float dppq(float x) {
#if __has_builtin(__builtin_amdgcn_update_dpp)
    int i = __builtin_bit_cast(int, x);
    int r = __builtin_amdgcn_update_dpp(i, i, CTRL, 0xF, 0xF, true);
    return __builtin_bit_cast(float, r);
#else
    return __shfl_xor(x, (CTRL == 177) ? 1 : (CTRL == 78) ? 2 : 3, 4);
#endif
}

// One workgroup per batch element; 512 threads.
// lane = 4k+gt: the 4 gates (i,f,g,o) of h-element j = wave*16+k live in one
// quad. Gate exchange via DPP quad_perm; c held redundantly in each quad lane.
// Single barrier per step; s_x/s_h double-buffered.
__global__ __launch_bounds__(512, 2) void lstm_fused_kernel(
    const float* __restrict__ input,  // [B,T,I]
    const float* __restrict__ h0,     // [B,H]
    const float* __restrict__ c0,     // [B,H]
    const float* __restrict__ W_ih,   // [4H,I]
    const float* __restrict__ W_hh,   // [4H,H]
    const float* __restrict__ b_ih,   // [4H]
    const float* __restrict__ b_hh,   // [4H]
    float* __restrict__ out)          // [B*H] h_last, then [B,T,H] encoded
{
    __shared__ __align__(16) h2 s_x[2][II / 2];   // double-buffered x_t (fp16)
    __shared__ __align__(16) h2 s_h[2][HH / 2];   // double-buffered h   (fp16)

    const int tid  = threadIdx.x;
    const int b    = blockIdx.x;
    const int lane = tid & 63;
    const int w    = tid >> 6;
    const int gt   = lane & 3;                  // 0=i 1=f 2=g 3=o
    const int j    = (w << 4) | (lane >> 2);    // h element [0,128)
    const int row  = (gt << 7) | j;             // weight row gt*128+j

    // ---- weight rows into registers, fp32 -> fp16x2 ----
    h2 wih[II / 2];   // 32 regs
    h2 whh[HH / 2];   // 64 regs
    {
        const float4* p = reinterpret_cast<const float4*>(W_ih + row * II);
#pragma unroll
        for (int q = 0; q < II / 4; ++q) {
            float4 v = p[q];
            wih[2 * q]     = mkh2(v.x, v.y);
            wih[2 * q + 1] = mkh2(v.z, v.w);
        }
    }
    {
        const float4* p = reinterpret_cast<const float4*>(W_hh + row * HH);
#pragma unroll
        for (int q = 0; q < HH / 4; ++q) {
            float4 v = p[q];
            whh[2 * q]     = mkh2(v.x, v.y);
            whh[2 * q + 1] = mkh2(v.z, v.w);
        }
    }
    const float bias = b_ih[row] + b_hh[row];

    // ---- state init ----
    float c = c0[(size_t)b * HH + j];            // redundant per quad
    if (tid < 64) {
        float2 hv = reinterpret_cast<const float2*>(h0 + (size_t)b * HH)[tid];
        s_h[0][tid] = mkh2(hv.x, hv.y);
    }

    // ---- x prefetch: threads 0..31 hold 4 future float2 of x ----
    const float2* xin = reinterpret_cast<const float2*>(input) + (size_t)b * TT * 32 + tid;
    float2 xb0, xb1, xb2, xb3;
    if (tid < 32) {
        xb0 = xin[(size_t)0 * 32];
        xb1 = xin[(size_t)1 * 32];
        xb2 = xin[(size_t)2 * 32];
        xb3 = xin[(size_t)3 * 32];
        s_x[0][tid] = mkh2(xb0.x, xb0.y);   // stage step 0
        xb0 = xin[(size_t)4 * 32];          // xb0 now holds x_4
    }
    __syncthreads();

    float* out_h = out;            // [B*H]
    float* out_e = out + BB * HH;  // [B*T*H]
    float hlast = 0.0f;

    // step t: read s_x/s_h[t&1]; xbn holds x_{t+1}, staged into buf (t+1)&1,
    // then refetched to x_{t+5}.
    auto step = [&](int t, float2& xbn) {
        const int cb = t & 1, nb = cb ^ 1;

        if (tid < 32) {
            s_x[nb][tid] = mkh2(xbn.x, xbn.y);
            int tn = t + 5; if (tn > TT - 1) tn = TT - 1;   // clamped, harmless
            xbn = xin[(size_t)tn * 32];
        }

        const uint4* sx4 = reinterpret_cast<const uint4*>(s_x[cb]);  // 8
        const uint4* sh4 = reinterpret_cast<const uint4*>(s_h[cb]);  // 16
        float a0 = bias, a1 = 0.0f, a2 = 0.0f, a3 = 0.0f;
#pragma unroll
        for (int q = 0; q < 8; ++q) {
            uint4 v = sx4[q];
            a0 = fdot2f(wih[4 * q + 0], u2h(v.x), a0);
            a1 = fdot2f(wih[4 * q + 1], u2h(v.y), a1);
            a2 = fdot2f(wih[4 * q + 2], u2h(v.z), a2);
            a3 = fdot2f(wih[4 * q + 3], u2h(v.w), a3);
        }
#pragma unroll
        for (int q = 0; q < 16; ++q) {
            uint4 v = sh4[q];
            a0 = fdot2f(whh[4 * q + 0], u2h(v.x), a0);
            a1 = fdot2f(whh[4 * q + 1], u2h(v.y), a1);
            a2 = fdot2f(whh[4 * q + 2], u2h(v.z), a2);
            a3 = fdot2f(whh[4 * q + 3], u2h(v.w), a3);
        }
        float gate = (a0 + a1) + (a2 + a3);

        // activation for own gate type (predicated, no divergence):
        // gt==2 -> tanh, else sigmoid
        float pre = (gt == 2) ? 2.0f * gate : gate;
        float sg  = rcp_fast(1.0f + __expf(-pre));
        float act = (gt == 2) ? fmaf(sg, 2.0f, -1.0f) : sg;

        // quad butterfly: v1 = lane^1, v2 = lane^2, v3 = lane^3
        float v0 = act;
        float v1 = dppq<177>(act);   // quad_perm [1,0,3,2]
        float v2 = dppq<78>(act);    // quad_perm [2,3,0,1]
        float v3 = dppq<27>(act);    // quad_perm [3,2,1,0]
        // v_k holds gate gt^k; select gate 0..3
        float sA = (gt & 1) ? v1 : v0;
        float sB = (gt & 1) ? v3 : v2;
        float sC = (gt & 1) ? v0 : v1;
        float sD = (gt & 1) ? v2 : v3;
        float iv = (gt & 2) ? sB : sA;
        float gv = (gt & 2) ? sA : sB;
        float fv = (gt & 2) ? sD : sC;
        float ov = (gt & 2) ? sC : sD;

        c = fmaf(fv, c, iv * gv);
        float hv = ov * tanh_fast(c);
        hlast = hv;

        if (gt == 0) reinterpret_cast<_Float16*>(s_h[nb])[j] = (_Float16)hv;
        if (gt == 1) out_e[((size_t)b * TT + t) * HH + j] = hv;

        __syncthreads();
    };

    for (int t0 = 0; t0 < TT; t0 += 4) {
        step(t0 + 0, xb1);
        step(t0 + 1, xb2);
        step(t0 + 2, xb3);
        step(t0 + 3, xb0);
    }

    if (gt == 2) out_h[(size_t)b * HH + j] = hlast;
}

extern "C" void kernel_launch(void* const* d_in, const int* in_sizes, int n_in,
                              void* d_out, int out_size, void* d_ws, size_t ws_size,
                              hipStream_t stream) {
    const float* input = (const float*)d_in[0];
    const float* h0    = (const float*)d_in[1];
    const float* c0    = (const float*)d_in[2];
    const float* W_ih  = (const float*)d_in[3];
    const float* W_hh  = (const float*)d_in[4];
    const float* b_ih  = (const float*)d_in[5];
    const float* b_hh  = (const float*)d_in[6];
    float* out = (float*)d_out;

    hipLaunchKernelGGL(lstm_fused_kernel, dim3(BB), dim3(GG), 0, stream,
                       input, h0, c0, W_ih, W_hh, b_ih, b_hh, out);
}